// Round 14
// baseline (93.827 us; speedup 1.0000x reference)
//
#include <hip/hip_runtime.h>
#include <math.h>

#define BB 8
#define CIN 256
#define HW 4096
#define BHW 32768          // B*HW
#define COUT 256
#define KTOT 2304          // CIN*9
#define WS_N (BB*9*HW)     // 294912 floats per param array

// ws layout (floats):
//   0        sy   [WS_N]
//   WS_N     sx   [WS_N]
//   2*WS_N   m    [WS_N]
//   3*WS_N   w16s [294912] (72 k-steps x 16KB fragment-ordered bf16)
#define WOFF2_OFF (4*WS_N)            // woff2 [256*9*28] (fallback paths)
#define ACC_OFF   (WOFF2_OFF + 64512) // accum [27][BHW] (fallback)
#define ATOMIC_NEED ((size_t)(ACC_OFF + 27*BHW) * 4)
#define XT_OFF    (ACC_OFF + 27*BHW)  // xT [B][HW][CIN] bf16 = 4194304 floats
#define NEED3     ((size_t)(XT_OFF + (BB*HW*CIN)/2) * 4)
#define WO16_OFF  (XT_OFF + (BB*HW*CIN)/2)   // wo16: 72 x 1024 bf16
#define NEED4     ((size_t)(WO16_OFF + 36864) * 4)

#define PQ 520             // B_lds q-row stride (elements)
#define NK2 36             // 72 k-steps, 2 per barrier window

typedef __bf16 bf16;
typedef __attribute__((ext_vector_type(8))) __bf16 bf16x8;
typedef __attribute__((ext_vector_type(4))) __bf16 bf16x4;
typedef __attribute__((ext_vector_type(4))) float f32x4;

// ---------------- fused prep: xpose (2048) | wconv (256) | wprep2 (72) ----------------
__global__ __launch_bounds__(256) void prep_kernel(
    const float* __restrict__ x, const float* __restrict__ w_dcn,
    const float* __restrict__ w_off,
    bf16* __restrict__ xt, bf16* __restrict__ w16, bf16* __restrict__ wo16)
{
  __shared__ float t[64][65];
  const int bx = blockIdx.x;
  const int tid = threadIdx.x;

  if (bx < 2048) {
    const int b  = bx >> 8;
    const int cb = (bx & 255) >> 6;
    const int pb = bx & 63;
    const int hi = tid >> 6, lo = tid & 63;
#pragma unroll
    for (int r = 0; r < 16; ++r) {
      int ci = r * 4 + hi;
      t[ci][lo] = x[((size_t)(b * 256 + cb * 64 + ci)) * HW + pb * 64 + lo];
    }
    __syncthreads();
#pragma unroll
    for (int r = 0; r < 16; ++r) {
      int p = r * 4 + hi;
      xt[((size_t)(b * HW + pb * 64 + p)) * 256 + cb * 64 + lo] = (bf16)t[lo][p];
    }
  } else if (bx < 2048 + 256) {
    const int co = bx - 2048;
    const int c  = tid;
    const int cblk = c >> 5, cin = c & 31, q = cin >> 3, j = cin & 7;
#pragma unroll
    for (int kk = 0; kk < 9; ++kk)
      w16[(size_t)(cblk * 9 + kk) * 8192 + (q * 256 + co) * 8 + j] =
        (bf16)w_dcn[(size_t)co * KTOT + c * 9 + kk];
  } else {
    const int ks = bx - 2304;
    const int cblk = ks / 9, kk = ks - cblk * 9;
    for (int idx = tid; idx < 1024; idx += 256) {
      int lk = idx >> 8, row = (idx >> 3) & 31, j = idx & 7;
      int c = cblk * 32 + lk * 8 + j;
      float v = (row < 27) ? w_off[(size_t)row * KTOT + c * 9 + kk] : 0.f;
      wo16[(size_t)ks * 1024 + idx] = (bf16)v;
    }
  }
}

// fallback standalone preps
__global__ __launch_bounds__(256) void xpose_kernel(
    const float* __restrict__ x, bf16* __restrict__ xt)
{
  __shared__ float t[64][65];
  const int tid = threadIdx.x;
  const int bx  = blockIdx.x;
  const int b   = bx >> 8;
  const int cb  = (bx & 255) >> 6;
  const int pb  = bx & 63;
  const int hi = tid >> 6, lo = tid & 63;
#pragma unroll
  for (int r = 0; r < 16; ++r) {
    int ci = r * 4 + hi;
    t[ci][lo] = x[((size_t)(b * 256 + cb * 64 + ci)) * HW + pb * 64 + lo];
  }
  __syncthreads();
#pragma unroll
  for (int r = 0; r < 16; ++r) {
    int p = r * 4 + hi;
    xt[((size_t)(b * HW + pb * 64 + p)) * 256 + cb * 64 + lo] = (bf16)t[lo][p];
  }
}

__global__ __launch_bounds__(256) void wconv_kernel(
    const float* __restrict__ w, bf16* __restrict__ o)
{
  const int co = blockIdx.x;
  const int c  = threadIdx.x;
  const int cblk = c >> 5, cin = c & 31, q = cin >> 3, j = cin & 7;
#pragma unroll
  for (int kk = 0; kk < 9; ++kk)
    o[(size_t)(cblk * 9 + kk) * 8192 + (q * 256 + co) * 8 + j] =
      (bf16)w[(size_t)co * KTOT + c * 9 + kk];
}

__global__ __launch_bounds__(256) void wprep_kernel(
    const float* __restrict__ w_off, float* __restrict__ woff2)
{
  const int c = blockIdx.x;
  const int tid = threadIdx.x;
  if (tid < 252) {
    int t = tid / 28, j = tid % 28;
    float v = (j < 27) ? w_off[(size_t)j * KTOT + c * 9 + t] : 0.f;
    woff2[((size_t)c * 9 + t) * 28 + j] = v;
  }
}

// ---------------- offconv_mfma2: 27(->32) x 2304 x BHW GEMM + fused transform ----------------
__global__ __launch_bounds__(256, 2) void offconv_mfma2_kernel(
    const bf16* __restrict__ xt, const bf16* __restrict__ wo16,
    const float* __restrict__ b_off, float* __restrict__ ws)
{
  __shared__ bf16 B_lds[2][8 * PQ];
  __shared__ float stage[32][66];

  const int tid  = threadIdx.x;
  const int b    = blockIdx.x & 7;
  const int pos0 = (blockIdx.x >> 3) * 64;

  const int lane = tid & 63, wid = tid >> 6;
  const int lm = lane & 15, lk = lane >> 4;
  const int gp = tid >> 2, gh = tid & 3;
  const int gpos = pos0 + gp;
  const int gho = gpos >> 6, gwo = gpos & 63;

  f32x4 acc[2];
  acc[0] = (f32x4){0.f, 0.f, 0.f, 0.f};
  acc[1] = (f32x4){0.f, 0.f, 0.f, 0.f};

  const bf16* bt  = xt + (size_t)b * HW * 256;
  const bf16* wga = wo16 + ((lk * 32 + lm) << 3);
  const bf16x8 zv = {};

  bf16x8 gA, gB;
  bool vA, vB;

#define OG(S, T, CB)                                                     \
  {                                                                      \
    int ky = (T) / 3, kx = (T) - 3 * (ky);                               \
    int yy = gho + ky - 1, xx = gwo + kx - 1;                            \
    v##S = ((unsigned)yy < 64u) && ((unsigned)xx < 64u);                 \
    int row = gpos + (ky - 1) * 64 + (kx - 1);                           \
    row = min(max(row, 0), HW - 1);                                      \
    g##S = *(const bf16x8*)(bt + ((size_t)row << 8) + (CB) + gh * 8);    \
  }

  OG(A, 0, 0); OG(B, 1, 0);
  *(bf16x8*)&B_lds[0][gh * PQ + gp * 8]       = vA ? gA : zv;
  *(bf16x8*)&B_lds[0][(4 + gh) * PQ + gp * 8] = vB ? gB : zv;
  OG(A, 2, 0); OG(B, 3, 0);
  asm volatile("s_waitcnt lgkmcnt(0)" ::: "memory");
  __builtin_amdgcn_sched_barrier(0);
  __builtin_amdgcn_s_barrier();

#pragma unroll 2
  for (int i = 0; i < NK2 - 1; ++i) {
    const int ri = i & 1, wi = ri ^ 1;
    const bf16* wg0 = wga + (size_t)(2 * i) * 1024;
    bf16x8 af00 = *(const bf16x8*)(wg0);
    bf16x8 af01 = *(const bf16x8*)(wg0 + 128);
    bf16x8 af10 = *(const bf16x8*)(wg0 + 1024);
    bf16x8 af11 = *(const bf16x8*)(wg0 + 1024 + 128);

    bf16x8 bf0 = *(const bf16x8*)&B_lds[ri][lk * PQ + (wid * 16 + lm) * 8];
    bf16x8 bf1 = *(const bf16x8*)&B_lds[ri][(4 + lk) * PQ + (wid * 16 + lm) * 8];

    *(bf16x8*)&B_lds[wi][gh * PQ + gp * 8]       = vA ? gA : zv;
    *(bf16x8*)&B_lds[wi][(4 + gh) * PQ + gp * 8] = vB ? gB : zv;

    {
      int ks0 = 2 * i + 4; if (ks0 > 70) ks0 = 70;
      int dA = ks0 / 9; int tA = ks0 - dA * 9; int cbA = dA * 32;
      int ks1 = ks0 + 1;
      int dB = ks1 / 9; int tB = ks1 - dB * 9; int cbB = dB * 32;
      OG(A, tA, cbA); OG(B, tB, cbB);
    }

    acc[0] = __builtin_amdgcn_mfma_f32_16x16x32_bf16(af00, bf0, acc[0], 0, 0, 0);
    acc[1] = __builtin_amdgcn_mfma_f32_16x16x32_bf16(af01, bf0, acc[1], 0, 0, 0);
    acc[0] = __builtin_amdgcn_mfma_f32_16x16x32_bf16(af10, bf1, acc[0], 0, 0, 0);
    acc[1] = __builtin_amdgcn_mfma_f32_16x16x32_bf16(af11, bf1, acc[1], 0, 0, 0);

    asm volatile("s_waitcnt lgkmcnt(0)" ::: "memory");
    __builtin_amdgcn_sched_barrier(0);
    __builtin_amdgcn_s_barrier();
  }

  {
    const bf16* wg0 = wga + (size_t)70 * 1024;
    bf16x8 af00 = *(const bf16x8*)(wg0);
    bf16x8 af01 = *(const bf16x8*)(wg0 + 128);
    bf16x8 af10 = *(const bf16x8*)(wg0 + 1024);
    bf16x8 af11 = *(const bf16x8*)(wg0 + 1024 + 128);
    bf16x8 bf0 = *(const bf16x8*)&B_lds[1][lk * PQ + (wid * 16 + lm) * 8];
    bf16x8 bf1 = *(const bf16x8*)&B_lds[1][(4 + lk) * PQ + (wid * 16 + lm) * 8];
    acc[0] = __builtin_amdgcn_mfma_f32_16x16x32_bf16(af00, bf0, acc[0], 0, 0, 0);
    acc[1] = __builtin_amdgcn_mfma_f32_16x16x32_bf16(af01, bf0, acc[1], 0, 0, 0);
    acc[0] = __builtin_amdgcn_mfma_f32_16x16x32_bf16(af10, bf1, acc[0], 0, 0, 0);
    acc[1] = __builtin_amdgcn_mfma_f32_16x16x32_bf16(af11, bf1, acc[1], 0, 0, 0);
  }

  __syncthreads();
#pragma unroll
  for (int fr = 0; fr < 2; ++fr)
#pragma unroll
    for (int r = 0; r < 4; ++r)
      stage[fr * 16 + lk * 4 + r][wid * 16 + lm] = acc[fr][r];
  __syncthreads();
  for (int t = tid; t < 576; t += 256) {
    int kk = t >> 6, p = t & 63;
    int pos = pos0 + p;
    int ho = pos >> 6, wo = pos & 63;
    float syv = stage[2 * kk][p]     + b_off[2 * kk]     + (float)(ho - 1 + kk / 3);
    float sxv = stage[2 * kk + 1][p] + b_off[2 * kk + 1] + (float)(wo - 1 + kk % 3);
    float mv  = stage[18 + kk][p]    + b_off[18 + kk];
    ws[(b * 9 + kk) * HW + pos]            = syv;
    ws[WS_N + (b * 9 + kk) * HW + pos]     = sxv;
    ws[2 * WS_N + (b * 9 + kk) * HW + pos] = 1.f / (1.f + expf(-mv));
  }
#undef OG
}

// ---------------- offconv fallbacks ----------------
template<int NS>
__global__ __launch_bounds__(256) void offconv_atom_kernel(
    const float* __restrict__ x, const float* __restrict__ woff2,
    float* __restrict__ accum)
{
  const int tid = threadIdx.x;
  const int bs  = blockIdx.x;
  const int st  = bs & 15;
  const int b   = (bs >> 4) & 7;
  const int s   = bs >> 7;
  const int pos = st * 256 + tid;
  const int ho  = pos >> 6, wo = pos & 63;
  const int c0  = s * (CIN / NS), c1 = c0 + CIN / NS;

  int   toff[9];
  float tvf[9];
#pragma unroll
  for (int t = 0; t < 9; ++t) {
    int ky = t / 3, kx = t % 3;
    int yy = ho - 1 + ky, xx = wo - 1 + kx;
    bool ok = ((unsigned)yy < 64u) && ((unsigned)xx < 64u);
    toff[t] = (min(max(yy, 0), 63)) * 64 + min(max(xx, 0), 63);
    tvf[t]  = ok ? 1.f : 0.f;
  }
  float a[27];
#pragma unroll
  for (int j = 0; j < 27; ++j) a[j] = 0.f;
  const float* xb = x + (size_t)b * CIN * HW;
#pragma unroll 2
  for (int c = c0; c < c1; ++c) {
    const float* xc = xb + (size_t)c * HW;
    float xv[9];
#pragma unroll
    for (int t = 0; t < 9; ++t) xv[t] = xc[toff[t]] * tvf[t];
    const float4* wr4 = (const float4*)(woff2 + (size_t)c * 252);
#pragma unroll
    for (int t = 0; t < 9; ++t) {
      float4 wb[7];
#pragma unroll
      for (int q = 0; q < 7; ++q) wb[q] = wr4[t * 7 + q];
#pragma unroll
      for (int q = 0; q < 7; ++q) {
        int j0 = q * 4;
        a[j0 + 0] = fmaf(wb[q].x, xv[t], a[j0 + 0]);
        a[j0 + 1] = fmaf(wb[q].y, xv[t], a[j0 + 1]);
        a[j0 + 2] = fmaf(wb[q].z, xv[t], a[j0 + 2]);
        if (j0 + 3 < 27) a[j0 + 3] = fmaf(wb[q].w, xv[t], a[j0 + 3]);
      }
    }
  }
  const int bp = b * HW + pos;
#pragma unroll
  for (int j = 0; j < 27; ++j)
    atomicAdd(&accum[(size_t)j * BHW + bp], a[j]);
}

__global__ __launch_bounds__(256) void combine_kernel(
    const float* __restrict__ b_off, float* __restrict__ ws)
{
  int gid = blockIdx.x * 256 + threadIdx.x;
  int kk = gid >> 15, bp = gid & 32767;
  int b = bp >> 12, pos = bp & 4095;
  int ho = pos >> 6, wo = pos & 63;
  const float* acc = ws + ACC_OFF;
  int jy = 2 * kk, jx = 2 * kk + 1, jm = 18 + kk;
  float syv = acc[(size_t)jy * BHW + bp] + b_off[jy] + (float)(ho - 1 + kk / 3);
  float sxv = acc[(size_t)jx * BHW + bp] + b_off[jx] + (float)(wo - 1 + kk % 3);
  float mv  = acc[(size_t)jm * BHW + bp] + b_off[jm];
  ws[(b * 9 + kk) * HW + pos]            = syv;
  ws[WS_N + (b * 9 + kk) * HW + pos]     = sxv;
  ws[2 * WS_N + (b * 9 + kk) * HW + pos] = 1.f / (1.f + expf(-mv));
}

// ---------------- dcn v11: v10 + A-fragment prefetch one window ahead ----------------
// 512 blocks, 4 waves. Wave wid owns co slice wid*64..+63 over ALL 64 pos (acc 4x4).
// A for window i is in regs (prefetched at window i-1) -> MFMA has zero vm-wait on A.
__global__ __launch_bounds__(256, 2) void dcn_mfma11_kernel(
    const bf16* __restrict__ xt, const bf16* __restrict__ w16,
    const float* __restrict__ b_dcn, const float* __restrict__ ws,
    float* __restrict__ out)
{
  __shared__ bf16 B_lds[2][8 * PQ];    // 16.6 KB
  __shared__ int2   pidx[576];
  __shared__ float4 pwts[576];         // folded {w00,w01,w10,w11}

  const int tid  = threadIdx.x;
  const int b    = blockIdx.x & 7;
  const int pos0 = (blockIdx.x >> 3) * 64;

  for (int t = tid; t < 576; t += 256) {
    int kk = t >> 6, p = t & 63;
    int pos = pos0 + p;
    float sy = ws[(b * 9 + kk) * HW + pos];
    float sx = ws[WS_N + (b * 9 + kk) * HW + pos];
    float m  = ws[2 * WS_N + (b * 9 + kk) * HW + pos];
    float y0f = floorf(sy), x0f = floorf(sx);
    int y0 = (int)y0f, x0 = (int)x0f;
    float wy = sy - y0f, wx = sx - x0f;
    int ix0 = min(max(x0, 0), 63), ix1 = min(max(x0 + 1, 0), 63);
    int bx  = min(max(x0, 0), 62);
    float vx0 = (x0 >= 0  && x0 <= 63) ? 1.f : 0.f;
    float vx1 = (x0 >= -1 && x0 <= 62) ? 1.f : 0.f;
    float wx0 = (1.f - wx) * vx0, wx1 = wx * vx1;
    float a0 = (ix0 == bx     ? wx0 : 0.f) + (ix1 == bx     ? wx1 : 0.f);
    float a1 = (ix0 == bx + 1 ? wx0 : 0.f) + (ix1 == bx + 1 ? wx1 : 0.f);
    int rb0 = min(max(y0, 0), 63), rb1 = min(max(y0 + 1, 0), 63);
    float vy0 = (y0 >= 0  && y0 <= 63) ? 1.f : 0.f;
    float vy1 = (y0 >= -1 && y0 <= 62) ? 1.f : 0.f;
    float wy0m = (1.f - wy) * vy0 * m, wy1m = wy * vy1 * m;
    pidx[t] = make_int2(rb0 * 64 + bx, rb1 * 64 + bx);
    pwts[t] = make_float4(a0 * wy0m, a1 * wy0m, a0 * wy1m, a1 * wy1m);
  }
  __syncthreads();

  const int lane = tid & 63, wid = tid >> 6;   // wid = co slice
  const int lm = lane & 15, lk = lane >> 4;
  const int chq = tid & 3;                     // 8-ch chunk within 32
  const int gp  = tid >> 2;                    // pos 0..63

  f32x4 acc[4][4];
#pragma unroll
  for (int a = 0; a < 4; ++a)
#pragma unroll
    for (int c = 0; c < 4; ++c)
      acc[a][c] = (f32x4){0.f, 0.f, 0.f, 0.f};

  const bf16* bt  = xt + (size_t)b * HW * 256;
  const bf16* wga = w16 + ((lk * 256 + wid * 64 + lm) << 3);
  const int wA = chq * PQ + gp * 8;            // k-step 0: q = chq
  const int wB = (4 + chq) * PQ + gp * 8;      // k-step 1

  float4 pwA, pwB;
  bf16x8 cA00, cA01, cA10, cA11, cB00, cB01, cB10, cB11;
  bf16x8 af0[4], af1[4];                       // A frags for CURRENT window

#define GATH(S, T, CB)                                                   \
  {                                                                      \
    int pb = (T) * 64 + gp;                                              \
    int2 pi = pidx[pb]; pw##S = pwts[pb];                                \
    const bf16* p0 = bt + ((size_t)pi.x << 8) + (CB) + (chq << 3);       \
    const bf16* p1 = bt + ((size_t)pi.y << 8) + (CB) + (chq << 3);       \
    c##S##00 = *(const bf16x8*)p0; c##S##01 = *(const bf16x8*)(p0 + 256);\
    c##S##10 = *(const bf16x8*)p1; c##S##11 = *(const bf16x8*)(p1 + 256);\
  }

#define COMB(S, DST)                                                     \
  {                                                                      \
    bf16x8 vv;                                                           \
    _Pragma("unroll")                                                    \
    for (int e = 0; e < 8; ++e) {                                        \
      float v = fmaf(pw##S.x, (float)c##S##00[e],                        \
                fmaf(pw##S.y, (float)c##S##01[e],                        \
                fmaf(pw##S.z, (float)c##S##10[e],                        \
                     pw##S.w * (float)c##S##11[e])));                    \
      vv[e] = (bf16)v;                                                   \
    }                                                                    \
    *(bf16x8*)(DST) = vv;                                                \
  }

  // ---- prologue: window 0 (k-steps 0,1) -> buf0; A(0) -> regs; gathers for window 1
  GATH(A, 0, 0); GATH(B, 1, 0);
  COMB(A, &B_lds[0][wA]);
  COMB(B, &B_lds[0][wB]);
#pragma unroll
  for (int fr = 0; fr < 4; ++fr) {
    af0[fr] = *(const bf16x8*)(wga + fr * 128);
    af1[fr] = *(const bf16x8*)(wga + 8192 + fr * 128);
  }
  GATH(A, 2, 0); GATH(B, 3, 0);
  asm volatile("s_waitcnt lgkmcnt(0)" ::: "memory");
  __builtin_amdgcn_sched_barrier(0);
  __builtin_amdgcn_s_barrier();

#pragma unroll 2
  for (int i = 0; i < NK2 - 1; ++i) {
    const int ri = i & 1, wi = ri ^ 1;

    // 1. B fragments for window i (LDS)
    bf16x8 bf0[4], bf1[4];
#pragma unroll
    for (int pf = 0; pf < 4; ++pf)
      bf0[pf] = *(const bf16x8*)&B_lds[ri][lk * PQ + (pf * 16 + lm) * 8];
#pragma unroll
    for (int pf = 0; pf < 4; ++pf)
      bf1[pf] = *(const bf16x8*)&B_lds[ri][(4 + lk) * PQ + (pf * 16 + lm) * 8];

    // 2. A prefetch for window i+1 (L2; consumed next window -> latency hidden)
    bf16x8 afn0[4], afn1[4];
    {
      const bf16* wgn = wga + (size_t)(2 * i + 2) * 8192;
#pragma unroll
      for (int fr = 0; fr < 4; ++fr) {
        afn0[fr] = *(const bf16x8*)(wgn + fr * 128);
        afn1[fr] = *(const bf16x8*)(wgn + 8192 + fr * 128);
      }
    }

    // 3. combine window i+1 (regs gathered last window) -> buf wi
    COMB(A, &B_lds[wi][wA]);
    COMB(B, &B_lds[wi][wB]);

    // 4. gathers for window i+2 (k-steps 2i+4, 2i+5; clamped)
    {
      int ks0 = 2 * i + 4; if (ks0 > 70) ks0 = 70;
      int dA = ks0 / 9; int tA = ks0 - dA * 9; int cbA = dA * 32;
      int ks1 = ks0 + 1;
      int dB = ks1 / 9; int tB = ks1 - dB * 9; int cbB = dB * 32;
      GATH(A, tA, cbA); GATH(B, tB, cbB);
    }

    // 5. MFMA: A from regs (no wait), B from LDS
#pragma unroll
    for (int fr = 0; fr < 4; ++fr)
#pragma unroll
      for (int pf = 0; pf < 4; ++pf)
        acc[fr][pf] = __builtin_amdgcn_mfma_f32_16x16x32_bf16(af0[fr], bf0[pf], acc[fr][pf], 0, 0, 0);
#pragma unroll
    for (int fr = 0; fr < 4; ++fr)
#pragma unroll
      for (int pf = 0; pf < 4; ++pf)
        acc[fr][pf] = __builtin_amdgcn_mfma_f32_16x16x32_bf16(af1[fr], bf1[pf], acc[fr][pf], 0, 0, 0);

    // 6. rotate A regs (unroll-2 renames away)
#pragma unroll
    for (int fr = 0; fr < 4; ++fr) { af0[fr] = afn0[fr]; af1[fr] = afn1[fr]; }

    asm volatile("s_waitcnt lgkmcnt(0)" ::: "memory");
    __builtin_amdgcn_sched_barrier(0);
    __builtin_amdgcn_s_barrier();
  }

  // ---- final window (k-steps 70,71) from buf1; A already prefetched
  {
    bf16x8 bf0[4], bf1[4];
#pragma unroll
    for (int pf = 0; pf < 4; ++pf) {
      bf0[pf] = *(const bf16x8*)&B_lds[1][lk * PQ + (pf * 16 + lm) * 8];
      bf1[pf] = *(const bf16x8*)&B_lds[1][(4 + lk) * PQ + (pf * 16 + lm) * 8];
    }
#pragma unroll
    for (int fr = 0; fr < 4; ++fr)
#pragma unroll
      for (int pf = 0; pf < 4; ++pf)
        acc[fr][pf] = __builtin_amdgcn_mfma_f32_16x16x32_bf16(af0[fr], bf0[pf], acc[fr][pf], 0, 0, 0);
#pragma unroll
    for (int fr = 0; fr < 4; ++fr)
#pragma unroll
      for (int pf = 0; pf < 4; ++pf)
        acc[fr][pf] = __builtin_amdgcn_mfma_f32_16x16x32_bf16(af1[fr], bf1[pf], acc[fr][pf], 0, 0, 0);
  }
#undef GATH
#undef COMB

  // ---- epilogue: bias + store (C/D: col=lane&15, row=(lane>>4)*4+reg)
#pragma unroll
  for (int fr = 0; fr < 4; ++fr) {
#pragma unroll
    for (int r = 0; r < 4; ++r) {
      int co = wid * 64 + fr * 16 + lk * 4 + r;
      float bias = b_dcn[co];
      float* orow = out + ((size_t)b * COUT + co) * HW + pos0;
#pragma unroll
      for (int pf = 0; pf < 4; ++pf)
        orow[pf * 16 + lm] = acc[fr][pf][r] + bias;
    }
  }
}

extern "C" void kernel_launch(void* const* d_in, const int* in_sizes, int n_in,
                              void* d_out, int out_size, void* d_ws, size_t ws_size,
                              hipStream_t stream) {
  const float* x     = (const float*)d_in[0];
  const float* w_off = (const float*)d_in[1];
  const float* b_off = (const float*)d_in[2];
  const float* w_dcn = (const float*)d_in[3];
  const float* b_dcn = (const float*)d_in[4];
  float* out = (float*)d_out;
  float* ws  = (float*)d_ws;
  bf16* w16  = (bf16*)(ws + 3 * WS_N);
  float* woff2 = ws + WOFF2_OFF;

  if (ws_size >= NEED4) {
    bf16* xt   = (bf16*)(ws + XT_OFF);
    bf16* wo16 = (bf16*)(ws + WO16_OFF);
    prep_kernel<<<2376, 256, 0, stream>>>(x, w_dcn, w_off, xt, w16, wo16);
    offconv_mfma2_kernel<<<BB * (HW / 64), 256, 0, stream>>>(xt, wo16, b_off, ws);
    dcn_mfma11_kernel<<<BB * (HW / 64), 256, 0, stream>>>(xt, w16, b_dcn, ws, out);
  } else if (ws_size >= NEED3) {
    bf16* xt = (bf16*)(ws + XT_OFF);
    wconv_kernel<<<COUT, 256, 0, stream>>>(w_dcn, w16);
    wprep_kernel<<<256, 256, 0, stream>>>(w_off, woff2);
    xpose_kernel<<<2048, 256, 0, stream>>>(x, xt);
    hipMemsetAsync(ws + ACC_OFF, 0, (size_t)27 * BHW * 4, stream);
    offconv_atom_kernel<8><<<8 * BB * 16, 256, 0, stream>>>(x, woff2, ws + ACC_OFF);
    combine_kernel<<<(9 * BHW) / 256, 256, 0, stream>>>(b_off, ws);
    dcn_mfma11_kernel<<<BB * (HW / 64), 256, 0, stream>>>(xt, w16, b_dcn, ws, out);
  } else {
    wconv_kernel<<<COUT, 256, 0, stream>>>(w_dcn, w16);
    wprep_kernel<<<256, 256, 0, stream>>>(w_off, woff2);
    bf16* xt = (bf16*)(ws + ACC_OFF);
    xpose_kernel<<<2048, 256, 0, stream>>>(x, xt);
    offconv_mfma2_kernel<<<BB * (HW / 64), 256, 0, stream>>>(
        xt, (bf16*)(ws + ACC_OFF), b_off, ws);  // degenerate; assumes ws >= NEED3 in practice
    dcn_mfma11_kernel<<<BB * (HW / 64), 256, 0, stream>>>(xt, w16, b_dcn, ws, out);
  }
}

// Round 15
// 87.843 us; speedup vs baseline: 1.0681x; 1.0681x over previous
//
#include <hip/hip_runtime.h>
#include <math.h>

#define BB 8
#define CIN 256
#define HW 4096
#define BHW 32768          // B*HW
#define COUT 256
#define KTOT 2304          // CIN*9
#define WS_N (BB*9*HW)     // 294912 floats per param array

// ws layout (floats):
//   0        sy   [WS_N]
//   WS_N     sx   [WS_N]
//   2*WS_N   m    [WS_N]
//   3*WS_N   w16s [294912] (72 k-steps x 16KB fragment-ordered f16)
#define WOFF2_OFF (4*WS_N)            // woff2 [256*9*28] (fallback paths)
#define ACC_OFF   (WOFF2_OFF + 64512) // accum [27][BHW] (fallback)
#define ATOMIC_NEED ((size_t)(ACC_OFF + 27*BHW) * 4)
#define XT_OFF    (ACC_OFF + 27*BHW)  // xT [B][HW][CIN] f16 = 4194304 floats
#define NEED3     ((size_t)(XT_OFF + (BB*HW*CIN)/2) * 4)
#define WO16_OFF  (XT_OFF + (BB*HW*CIN)/2)   // wo16: 72 x 1024 f16
#define NEED4     ((size_t)(WO16_OFF + 36864) * 4)

#define PQ 520             // B_lds q-row stride (elements)
#define NK2 36             // 72 k-steps, 2 per barrier window

typedef _Float16 hf;
typedef __attribute__((ext_vector_type(8))) _Float16 hfx8;
typedef __attribute__((ext_vector_type(4))) float f32x4;

// ---------------- fused prep: xpose (2048) | wconv (256) | wprep2 (72) ----------------
__global__ __launch_bounds__(256) void prep_kernel(
    const float* __restrict__ x, const float* __restrict__ w_dcn,
    const float* __restrict__ w_off,
    hf* __restrict__ xt, hf* __restrict__ w16, hf* __restrict__ wo16)
{
  __shared__ float t[64][65];
  const int bx = blockIdx.x;
  const int tid = threadIdx.x;

  if (bx < 2048) {
    const int b  = bx >> 8;
    const int cb = (bx & 255) >> 6;
    const int pb = bx & 63;
    const int hi = tid >> 6, lo = tid & 63;
#pragma unroll
    for (int r = 0; r < 16; ++r) {
      int ci = r * 4 + hi;
      t[ci][lo] = x[((size_t)(b * 256 + cb * 64 + ci)) * HW + pb * 64 + lo];
    }
    __syncthreads();
#pragma unroll
    for (int r = 0; r < 16; ++r) {
      int p = r * 4 + hi;
      xt[((size_t)(b * HW + pb * 64 + p)) * 256 + cb * 64 + lo] = (hf)t[lo][p];
    }
  } else if (bx < 2048 + 256) {
    const int co = bx - 2048;
    const int c  = tid;
    const int cblk = c >> 5, cin = c & 31, q = cin >> 3, j = cin & 7;
#pragma unroll
    for (int kk = 0; kk < 9; ++kk)
      w16[(size_t)(cblk * 9 + kk) * 8192 + (q * 256 + co) * 8 + j] =
        (hf)w_dcn[(size_t)co * KTOT + c * 9 + kk];
  } else {
    const int ks = bx - 2304;
    const int cblk = ks / 9, kk = ks - cblk * 9;
    for (int idx = tid; idx < 1024; idx += 256) {
      int lk = idx >> 8, row = (idx >> 3) & 31, j = idx & 7;
      int c = cblk * 32 + lk * 8 + j;
      float v = (row < 27) ? w_off[(size_t)row * KTOT + c * 9 + kk] : 0.f;
      wo16[(size_t)ks * 1024 + idx] = (hf)v;
    }
  }
}

// fallback standalone preps
__global__ __launch_bounds__(256) void xpose_kernel(
    const float* __restrict__ x, hf* __restrict__ xt)
{
  __shared__ float t[64][65];
  const int tid = threadIdx.x;
  const int bx  = blockIdx.x;
  const int b   = bx >> 8;
  const int cb  = (bx & 255) >> 6;
  const int pb  = bx & 63;
  const int hi = tid >> 6, lo = tid & 63;
#pragma unroll
  for (int r = 0; r < 16; ++r) {
    int ci = r * 4 + hi;
    t[ci][lo] = x[((size_t)(b * 256 + cb * 64 + ci)) * HW + pb * 64 + lo];
  }
  __syncthreads();
#pragma unroll
  for (int r = 0; r < 16; ++r) {
    int p = r * 4 + hi;
    xt[((size_t)(b * HW + pb * 64 + p)) * 256 + cb * 64 + lo] = (hf)t[lo][p];
  }
}

__global__ __launch_bounds__(256) void wconv_kernel(
    const float* __restrict__ w, hf* __restrict__ o)
{
  const int co = blockIdx.x;
  const int c  = threadIdx.x;
  const int cblk = c >> 5, cin = c & 31, q = cin >> 3, j = cin & 7;
#pragma unroll
  for (int kk = 0; kk < 9; ++kk)
    o[(size_t)(cblk * 9 + kk) * 8192 + (q * 256 + co) * 8 + j] =
      (hf)w[(size_t)co * KTOT + c * 9 + kk];
}

__global__ __launch_bounds__(256) void wprep_kernel(
    const float* __restrict__ w_off, float* __restrict__ woff2)
{
  const int c = blockIdx.x;
  const int tid = threadIdx.x;
  if (tid < 252) {
    int t = tid / 28, j = tid % 28;
    float v = (j < 27) ? w_off[(size_t)j * KTOT + c * 9 + t] : 0.f;
    woff2[((size_t)c * 9 + t) * 28 + j] = v;
  }
}

// ---------------- offconv_mfma2: 27(->32) x 2304 x BHW GEMM + fused transform ----------------
__global__ __launch_bounds__(256, 2) void offconv_mfma2_kernel(
    const hf* __restrict__ xt, const hf* __restrict__ wo16,
    const float* __restrict__ b_off, float* __restrict__ ws)
{
  __shared__ hf B_lds[2][8 * PQ];
  __shared__ float stage[32][66];

  const int tid  = threadIdx.x;
  const int b    = blockIdx.x & 7;
  const int pos0 = (blockIdx.x >> 3) * 64;

  const int lane = tid & 63, wid = tid >> 6;
  const int lm = lane & 15, lk = lane >> 4;
  const int gp = tid >> 2, gh = tid & 3;
  const int gpos = pos0 + gp;
  const int gho = gpos >> 6, gwo = gpos & 63;

  f32x4 acc[2];
  acc[0] = (f32x4){0.f, 0.f, 0.f, 0.f};
  acc[1] = (f32x4){0.f, 0.f, 0.f, 0.f};

  const hf* bt  = xt + (size_t)b * HW * 256;
  const hf* wga = wo16 + ((lk * 32 + lm) << 3);
  const hfx8 zv = {};

  hfx8 gA, gB;
  bool vA, vB;

#define OG(S, T, CB)                                                     \
  {                                                                      \
    int ky = (T) / 3, kx = (T) - 3 * (ky);                               \
    int yy = gho + ky - 1, xx = gwo + kx - 1;                            \
    v##S = ((unsigned)yy < 64u) && ((unsigned)xx < 64u);                 \
    int row = gpos + (ky - 1) * 64 + (kx - 1);                           \
    row = min(max(row, 0), HW - 1);                                      \
    g##S = *(const hfx8*)(bt + ((size_t)row << 8) + (CB) + gh * 8);      \
  }

  OG(A, 0, 0); OG(B, 1, 0);
  *(hfx8*)&B_lds[0][gh * PQ + gp * 8]       = vA ? gA : zv;
  *(hfx8*)&B_lds[0][(4 + gh) * PQ + gp * 8] = vB ? gB : zv;
  OG(A, 2, 0); OG(B, 3, 0);
  asm volatile("s_waitcnt lgkmcnt(0)" ::: "memory");
  __builtin_amdgcn_sched_barrier(0);
  __builtin_amdgcn_s_barrier();

#pragma unroll 2
  for (int i = 0; i < NK2 - 1; ++i) {
    const int ri = i & 1, wi = ri ^ 1;
    const hf* wg0 = wga + (size_t)(2 * i) * 1024;
    hfx8 af00 = *(const hfx8*)(wg0);
    hfx8 af01 = *(const hfx8*)(wg0 + 128);
    hfx8 af10 = *(const hfx8*)(wg0 + 1024);
    hfx8 af11 = *(const hfx8*)(wg0 + 1024 + 128);

    hfx8 bf0 = *(const hfx8*)&B_lds[ri][lk * PQ + (wid * 16 + lm) * 8];
    hfx8 bf1 = *(const hfx8*)&B_lds[ri][(4 + lk) * PQ + (wid * 16 + lm) * 8];

    *(hfx8*)&B_lds[wi][gh * PQ + gp * 8]       = vA ? gA : zv;
    *(hfx8*)&B_lds[wi][(4 + gh) * PQ + gp * 8] = vB ? gB : zv;

    {
      int ks0 = 2 * i + 4; if (ks0 > 70) ks0 = 70;
      int dA = ks0 / 9; int tA = ks0 - dA * 9; int cbA = dA * 32;
      int ks1 = ks0 + 1;
      int dB = ks1 / 9; int tB = ks1 - dB * 9; int cbB = dB * 32;
      OG(A, tA, cbA); OG(B, tB, cbB);
    }

    acc[0] = __builtin_amdgcn_mfma_f32_16x16x32_f16(af00, bf0, acc[0], 0, 0, 0);
    acc[1] = __builtin_amdgcn_mfma_f32_16x16x32_f16(af01, bf0, acc[1], 0, 0, 0);
    acc[0] = __builtin_amdgcn_mfma_f32_16x16x32_f16(af10, bf1, acc[0], 0, 0, 0);
    acc[1] = __builtin_amdgcn_mfma_f32_16x16x32_f16(af11, bf1, acc[1], 0, 0, 0);

    asm volatile("s_waitcnt lgkmcnt(0)" ::: "memory");
    __builtin_amdgcn_sched_barrier(0);
    __builtin_amdgcn_s_barrier();
  }

  {
    const hf* wg0 = wga + (size_t)70 * 1024;
    hfx8 af00 = *(const hfx8*)(wg0);
    hfx8 af01 = *(const hfx8*)(wg0 + 128);
    hfx8 af10 = *(const hfx8*)(wg0 + 1024);
    hfx8 af11 = *(const hfx8*)(wg0 + 1024 + 128);
    hfx8 bf0 = *(const hfx8*)&B_lds[1][lk * PQ + (wid * 16 + lm) * 8];
    hfx8 bf1 = *(const hfx8*)&B_lds[1][(4 + lk) * PQ + (wid * 16 + lm) * 8];
    acc[0] = __builtin_amdgcn_mfma_f32_16x16x32_f16(af00, bf0, acc[0], 0, 0, 0);
    acc[1] = __builtin_amdgcn_mfma_f32_16x16x32_f16(af01, bf0, acc[1], 0, 0, 0);
    acc[0] = __builtin_amdgcn_mfma_f32_16x16x32_f16(af10, bf1, acc[0], 0, 0, 0);
    acc[1] = __builtin_amdgcn_mfma_f32_16x16x32_f16(af11, bf1, acc[1], 0, 0, 0);
  }

  __syncthreads();
#pragma unroll
  for (int fr = 0; fr < 2; ++fr)
#pragma unroll
    for (int r = 0; r < 4; ++r)
      stage[fr * 16 + lk * 4 + r][wid * 16 + lm] = acc[fr][r];
  __syncthreads();
  for (int t = tid; t < 576; t += 256) {
    int kk = t >> 6, p = t & 63;
    int pos = pos0 + p;
    int ho = pos >> 6, wo = pos & 63;
    float syv = stage[2 * kk][p]     + b_off[2 * kk]     + (float)(ho - 1 + kk / 3);
    float sxv = stage[2 * kk + 1][p] + b_off[2 * kk + 1] + (float)(wo - 1 + kk % 3);
    float mv  = stage[18 + kk][p]    + b_off[18 + kk];
    ws[(b * 9 + kk) * HW + pos]            = syv;
    ws[WS_N + (b * 9 + kk) * HW + pos]     = sxv;
    ws[2 * WS_N + (b * 9 + kk) * HW + pos] = 1.f / (1.f + expf(-mv));
  }
#undef OG
}

// ---------------- offconv fallbacks ----------------
template<int NS>
__global__ __launch_bounds__(256) void offconv_atom_kernel(
    const float* __restrict__ x, const float* __restrict__ woff2,
    float* __restrict__ accum)
{
  const int tid = threadIdx.x;
  const int bs  = blockIdx.x;
  const int st  = bs & 15;
  const int b   = (bs >> 4) & 7;
  const int s   = bs >> 7;
  const int pos = st * 256 + tid;
  const int ho  = pos >> 6, wo = pos & 63;
  const int c0  = s * (CIN / NS), c1 = c0 + CIN / NS;

  int   toff[9];
  float tvf[9];
#pragma unroll
  for (int t = 0; t < 9; ++t) {
    int ky = t / 3, kx = t % 3;
    int yy = ho - 1 + ky, xx = wo - 1 + kx;
    bool ok = ((unsigned)yy < 64u) && ((unsigned)xx < 64u);
    toff[t] = (min(max(yy, 0), 63)) * 64 + min(max(xx, 0), 63);
    tvf[t]  = ok ? 1.f : 0.f;
  }
  float a[27];
#pragma unroll
  for (int j = 0; j < 27; ++j) a[j] = 0.f;
  const float* xb = x + (size_t)b * CIN * HW;
#pragma unroll 2
  for (int c = c0; c < c1; ++c) {
    const float* xc = xb + (size_t)c * HW;
    float xv[9];
#pragma unroll
    for (int t = 0; t < 9; ++t) xv[t] = xc[toff[t]] * tvf[t];
    const float4* wr4 = (const float4*)(woff2 + (size_t)c * 252);
#pragma unroll
    for (int t = 0; t < 9; ++t) {
      float4 wb[7];
#pragma unroll
      for (int q = 0; q < 7; ++q) wb[q] = wr4[t * 7 + q];
#pragma unroll
      for (int q = 0; q < 7; ++q) {
        int j0 = q * 4;
        a[j0 + 0] = fmaf(wb[q].x, xv[t], a[j0 + 0]);
        a[j0 + 1] = fmaf(wb[q].y, xv[t], a[j0 + 1]);
        a[j0 + 2] = fmaf(wb[q].z, xv[t], a[j0 + 2]);
        if (j0 + 3 < 27) a[j0 + 3] = fmaf(wb[q].w, xv[t], a[j0 + 3]);
      }
    }
  }
  const int bp = b * HW + pos;
#pragma unroll
  for (int j = 0; j < 27; ++j)
    atomicAdd(&accum[(size_t)j * BHW + bp], a[j]);
}

__global__ __launch_bounds__(256) void combine_kernel(
    const float* __restrict__ b_off, float* __restrict__ ws)
{
  int gid = blockIdx.x * 256 + threadIdx.x;
  int kk = gid >> 15, bp = gid & 32767;
  int b = bp >> 12, pos = bp & 4095;
  int ho = pos >> 6, wo = pos & 63;
  const float* acc = ws + ACC_OFF;
  int jy = 2 * kk, jx = 2 * kk + 1, jm = 18 + kk;
  float syv = acc[(size_t)jy * BHW + bp] + b_off[jy] + (float)(ho - 1 + kk / 3);
  float sxv = acc[(size_t)jx * BHW + bp] + b_off[jx] + (float)(wo - 1 + kk % 3);
  float mv  = acc[(size_t)jm * BHW + bp] + b_off[jm];
  ws[(b * 9 + kk) * HW + pos]            = syv;
  ws[WS_N + (b * 9 + kk) * HW + pos]     = sxv;
  ws[2 * WS_N + (b * 9 + kk) * HW + pos] = 1.f / (1.f + expf(-mv));
}

// ---------------- dcn v12: v10 structure, f16 datapath + packed-f16 combine ----------------
// 512 blocks, 4 waves. Wave wid owns co slice wid*64..+63 over ALL 64 pos (acc 4x4).
__global__ __launch_bounds__(256, 2) void dcn_mfma12_kernel(
    const hf* __restrict__ xt, const hf* __restrict__ w16,
    const float* __restrict__ b_dcn, const float* __restrict__ ws,
    float* __restrict__ out)
{
  __shared__ hf B_lds[2][8 * PQ];      // 16.6 KB
  __shared__ int2   pidx[576];
  __shared__ float4 pwts[576];         // folded {w00,w01,w10,w11}

  const int tid  = threadIdx.x;
  const int b    = blockIdx.x & 7;
  const int pos0 = (blockIdx.x >> 3) * 64;

  for (int t = tid; t < 576; t += 256) {
    int kk = t >> 6, p = t & 63;
    int pos = pos0 + p;
    float sy = ws[(b * 9 + kk) * HW + pos];
    float sx = ws[WS_N + (b * 9 + kk) * HW + pos];
    float m  = ws[2 * WS_N + (b * 9 + kk) * HW + pos];
    float y0f = floorf(sy), x0f = floorf(sx);
    int y0 = (int)y0f, x0 = (int)x0f;
    float wy = sy - y0f, wx = sx - x0f;
    int ix0 = min(max(x0, 0), 63), ix1 = min(max(x0 + 1, 0), 63);
    int bx  = min(max(x0, 0), 62);
    float vx0 = (x0 >= 0  && x0 <= 63) ? 1.f : 0.f;
    float vx1 = (x0 >= -1 && x0 <= 62) ? 1.f : 0.f;
    float wx0 = (1.f - wx) * vx0, wx1 = wx * vx1;
    float a0 = (ix0 == bx     ? wx0 : 0.f) + (ix1 == bx     ? wx1 : 0.f);
    float a1 = (ix0 == bx + 1 ? wx0 : 0.f) + (ix1 == bx + 1 ? wx1 : 0.f);
    int rb0 = min(max(y0, 0), 63), rb1 = min(max(y0 + 1, 0), 63);
    float vy0 = (y0 >= 0  && y0 <= 63) ? 1.f : 0.f;
    float vy1 = (y0 >= -1 && y0 <= 62) ? 1.f : 0.f;
    float wy0m = (1.f - wy) * vy0 * m, wy1m = wy * vy1 * m;
    pidx[t] = make_int2(rb0 * 64 + bx, rb1 * 64 + bx);
    pwts[t] = make_float4(a0 * wy0m, a1 * wy0m, a0 * wy1m, a1 * wy1m);
  }
  __syncthreads();

  const int lane = tid & 63, wid = tid >> 6;   // wid = co slice
  const int lm = lane & 15, lk = lane >> 4;
  const int chq = tid & 3;                     // 8-ch chunk within 32
  const int gp  = tid >> 2;                    // pos 0..63

  f32x4 acc[4][4];
#pragma unroll
  for (int a = 0; a < 4; ++a)
#pragma unroll
    for (int c = 0; c < 4; ++c)
      acc[a][c] = (f32x4){0.f, 0.f, 0.f, 0.f};

  const hf* bt  = xt + (size_t)b * HW * 256;
  const hf* wga = w16 + ((lk * 256 + wid * 64 + lm) << 3);
  const int wA = chq * PQ + gp * 8;            // k-step 0: q = chq
  const int wB = (4 + chq) * PQ + gp * 8;      // k-step 1

  hf hwA0, hwA1, hwA2, hwA3, hwB0, hwB1, hwB2, hwB3;
  hfx8 cA00, cA01, cA10, cA11, cB00, cB01, cB10, cB11;

#define GATH(S, T, CB)                                                   \
  {                                                                      \
    int pb = (T) * 64 + gp;                                              \
    int2 pi = pidx[pb]; float4 pw = pwts[pb];                            \
    hw##S##0 = (hf)pw.x; hw##S##1 = (hf)pw.y;                            \
    hw##S##2 = (hf)pw.z; hw##S##3 = (hf)pw.w;                            \
    const hf* p0 = bt + ((size_t)pi.x << 8) + (CB) + (chq << 3);         \
    const hf* p1 = bt + ((size_t)pi.y << 8) + (CB) + (chq << 3);         \
    c##S##00 = *(const hfx8*)p0; c##S##01 = *(const hfx8*)(p0 + 256);    \
    c##S##10 = *(const hfx8*)p1; c##S##11 = *(const hfx8*)(p1 + 256);    \
  }

#define COMB(S, DST)                                                     \
  {                                                                      \
    hfx8 vv = c##S##00 * hw##S##0;                                       \
    vv += c##S##01 * hw##S##1;                                           \
    vv += c##S##10 * hw##S##2;                                           \
    vv += c##S##11 * hw##S##3;                                           \
    *(hfx8*)(DST) = vv;                                                  \
  }

  // ---- prologue: window 0 (k-steps 0,1) -> buf0; gathers for window 1 (2,3)
  GATH(A, 0, 0); GATH(B, 1, 0);
  COMB(A, &B_lds[0][wA]);
  COMB(B, &B_lds[0][wB]);
  GATH(A, 2, 0); GATH(B, 3, 0);
  asm volatile("s_waitcnt lgkmcnt(0)" ::: "memory");
  __builtin_amdgcn_sched_barrier(0);
  __builtin_amdgcn_s_barrier();

#pragma unroll 2
  for (int i = 0; i < NK2 - 1; ++i) {
    const int ri = i & 1, wi = ri ^ 1;

    const hf* wg0 = wga + (size_t)(2 * i) * 8192;
    hfx8 af0[4], af1[4];
#pragma unroll
    for (int fr = 0; fr < 4; ++fr) af0[fr] = *(const hfx8*)(wg0 + fr * 128);

    hfx8 bf0[4], bf1[4];
#pragma unroll
    for (int pf = 0; pf < 4; ++pf)
      bf0[pf] = *(const hfx8*)&B_lds[ri][lk * PQ + (pf * 16 + lm) * 8];
#pragma unroll
    for (int fr = 0; fr < 4; ++fr) af1[fr] = *(const hfx8*)(wg0 + 8192 + fr * 128);
#pragma unroll
    for (int pf = 0; pf < 4; ++pf)
      bf1[pf] = *(const hfx8*)&B_lds[ri][(4 + lk) * PQ + (pf * 16 + lm) * 8];

    COMB(A, &B_lds[wi][wA]);
    COMB(B, &B_lds[wi][wB]);

    {
      int ks0 = 2 * i + 4; if (ks0 > 70) ks0 = 70;
      int dA = ks0 / 9; int tA = ks0 - dA * 9; int cbA = dA * 32;
      int ks1 = ks0 + 1;
      int dB = ks1 / 9; int tB = ks1 - dB * 9; int cbB = dB * 32;
      GATH(A, tA, cbA); GATH(B, tB, cbB);
    }

#pragma unroll
    for (int fr = 0; fr < 4; ++fr)
#pragma unroll
      for (int pf = 0; pf < 4; ++pf)
        acc[fr][pf] = __builtin_amdgcn_mfma_f32_16x16x32_f16(af0[fr], bf0[pf], acc[fr][pf], 0, 0, 0);
#pragma unroll
    for (int fr = 0; fr < 4; ++fr)
#pragma unroll
      for (int pf = 0; pf < 4; ++pf)
        acc[fr][pf] = __builtin_amdgcn_mfma_f32_16x16x32_f16(af1[fr], bf1[pf], acc[fr][pf], 0, 0, 0);

    asm volatile("s_waitcnt lgkmcnt(0)" ::: "memory");
    __builtin_amdgcn_sched_barrier(0);
    __builtin_amdgcn_s_barrier();
  }

  // ---- final window (k-steps 70,71) from buf1
  {
    const hf* wg0 = wga + (size_t)70 * 8192;
    hfx8 af0[4], af1[4];
#pragma unroll
    for (int fr = 0; fr < 4; ++fr) af0[fr] = *(const hfx8*)(wg0 + fr * 128);
#pragma unroll
    for (int fr = 0; fr < 4; ++fr) af1[fr] = *(const hfx8*)(wg0 + 8192 + fr * 128);
    hfx8 bf0[4], bf1[4];
#pragma unroll
    for (int pf = 0; pf < 4; ++pf) {
      bf0[pf] = *(const hfx8*)&B_lds[1][lk * PQ + (pf * 16 + lm) * 8];
      bf1[pf] = *(const hfx8*)&B_lds[1][(4 + lk) * PQ + (pf * 16 + lm) * 8];
    }
#pragma unroll
    for (int fr = 0; fr < 4; ++fr)
#pragma unroll
      for (int pf = 0; pf < 4; ++pf)
        acc[fr][pf] = __builtin_amdgcn_mfma_f32_16x16x32_f16(af0[fr], bf0[pf], acc[fr][pf], 0, 0, 0);
#pragma unroll
    for (int fr = 0; fr < 4; ++fr)
#pragma unroll
      for (int pf = 0; pf < 4; ++pf)
        acc[fr][pf] = __builtin_amdgcn_mfma_f32_16x16x32_f16(af1[fr], bf1[pf], acc[fr][pf], 0, 0, 0);
  }
#undef GATH
#undef COMB

  // ---- epilogue: bias + store (C/D: col=lane&15, row=(lane>>4)*4+reg)
#pragma unroll
  for (int fr = 0; fr < 4; ++fr) {
#pragma unroll
    for (int r = 0; r < 4; ++r) {
      int co = wid * 64 + fr * 16 + lk * 4 + r;
      float bias = b_dcn[co];
      float* orow = out + ((size_t)b * COUT + co) * HW + pos0;
#pragma unroll
      for (int pf = 0; pf < 4; ++pf)
        orow[pf * 16 + lm] = acc[fr][pf][r] + bias;
    }
  }
}

extern "C" void kernel_launch(void* const* d_in, const int* in_sizes, int n_in,
                              void* d_out, int out_size, void* d_ws, size_t ws_size,
                              hipStream_t stream) {
  const float* x     = (const float*)d_in[0];
  const float* w_off = (const float*)d_in[1];
  const float* b_off = (const float*)d_in[2];
  const float* w_dcn = (const float*)d_in[3];
  const float* b_dcn = (const float*)d_in[4];
  float* out = (float*)d_out;
  float* ws  = (float*)d_ws;
  hf* w16  = (hf*)(ws + 3 * WS_N);
  float* woff2 = ws + WOFF2_OFF;

  if (ws_size >= NEED4) {
    hf* xt   = (hf*)(ws + XT_OFF);
    hf* wo16 = (hf*)(ws + WO16_OFF);
    prep_kernel<<<2376, 256, 0, stream>>>(x, w_dcn, w_off, xt, w16, wo16);
    offconv_mfma2_kernel<<<BB * (HW / 64), 256, 0, stream>>>(xt, wo16, b_off, ws);
    dcn_mfma12_kernel<<<BB * (HW / 64), 256, 0, stream>>>(xt, w16, b_dcn, ws, out);
  } else if (ws_size >= NEED3) {
    hf* xt = (hf*)(ws + XT_OFF);
    wconv_kernel<<<COUT, 256, 0, stream>>>(w_dcn, w16);
    wprep_kernel<<<256, 256, 0, stream>>>(w_off, woff2);
    xpose_kernel<<<2048, 256, 0, stream>>>(x, xt);
    hipMemsetAsync(ws + ACC_OFF, 0, (size_t)27 * BHW * 4, stream);
    offconv_atom_kernel<8><<<8 * BB * 16, 256, 0, stream>>>(x, woff2, ws + ACC_OFF);
    combine_kernel<<<(9 * BHW) / 256, 256, 0, stream>>>(b_off, ws);
    dcn_mfma12_kernel<<<BB * (HW / 64), 256, 0, stream>>>(xt, w16, b_dcn, ws, out);
  } else {
    wconv_kernel<<<COUT, 256, 0, stream>>>(w_dcn, w16);
    wprep_kernel<<<256, 256, 0, stream>>>(w_off, woff2);
    hf* xt = (hf*)(ws + ACC_OFF);
    xpose_kernel<<<2048, 256, 0, stream>>>(x, xt);
    offconv_mfma2_kernel<<<BB * (HW / 64), 256, 0, stream>>>(
        xt, (hf*)(ws + ACC_OFF), b_off, ws);  // degenerate; assumes ws >= NEED3 in practice
    dcn_mfma12_kernel<<<BB * (HW / 64), 256, 0, stream>>>(xt, w16, b_dcn, ws, out);
  }
}

// Round 16
// 82.604 us; speedup vs baseline: 1.1359x; 1.0634x over previous
//
#include <hip/hip_runtime.h>
#include <math.h>

#define BB 8
#define CIN 256
#define HW 4096
#define BHW 32768          // B*HW
#define COUT 256
#define KTOT 2304          // CIN*9
#define WS_N (BB*9*HW)     // 294912 floats per param array

// ws layout (floats):
//   0        sy   [WS_N]   (fallback paths only)
//   WS_N     sx   [WS_N]
//   2*WS_N   m    [WS_N]
//   3*WS_N   w16s [294912] (72 k-steps x 16KB fragment-ordered f16)
#define WOFF2_OFF (4*WS_N)            // woff2 [256*9*28] (fallback paths)
#define ACC_OFF   (WOFF2_OFF + 64512) // accum [27][BHW] (fallback)
#define ATOMIC_NEED ((size_t)(ACC_OFF + 27*BHW) * 4)
#define XT_OFF    (ACC_OFF + 27*BHW)  // xT [B][HW][CIN] f16 = 4194304 floats
#define NEED3     ((size_t)(XT_OFF + (BB*HW*CIN)/2) * 4)
#define WO16_OFF  (XT_OFF + (BB*HW*CIN)/2)   // wo16: 72 x 1024 f16
#define NEED4     ((size_t)(WO16_OFF + 36864) * 4)

#define PQ 520             // B_lds q-row stride (elements)
#define NK2 36             // 72 k-steps, 2 per barrier window

typedef _Float16 hf;
typedef __attribute__((ext_vector_type(8))) _Float16 hfx8;
typedef __attribute__((ext_vector_type(4))) float f32x4;

// ---------------- fused prep: xpose (2048) | wconv (256) | wprep2 (72) ----------------
__global__ __launch_bounds__(256) void prep_kernel(
    const float* __restrict__ x, const float* __restrict__ w_dcn,
    const float* __restrict__ w_off,
    hf* __restrict__ xt, hf* __restrict__ w16, hf* __restrict__ wo16)
{
  __shared__ float t[64][65];
  const int bx = blockIdx.x;
  const int tid = threadIdx.x;

  if (bx < 2048) {
    const int b  = bx >> 8;
    const int cb = (bx & 255) >> 6;
    const int pb = bx & 63;
    const int hi = tid >> 6, lo = tid & 63;
#pragma unroll
    for (int r = 0; r < 16; ++r) {
      int ci = r * 4 + hi;
      t[ci][lo] = x[((size_t)(b * 256 + cb * 64 + ci)) * HW + pb * 64 + lo];
    }
    __syncthreads();
#pragma unroll
    for (int r = 0; r < 16; ++r) {
      int p = r * 4 + hi;
      xt[((size_t)(b * HW + pb * 64 + p)) * 256 + cb * 64 + lo] = (hf)t[lo][p];
    }
  } else if (bx < 2048 + 256) {
    const int co = bx - 2048;
    const int c  = tid;
    const int cblk = c >> 5, cin = c & 31, q = cin >> 3, j = cin & 7;
#pragma unroll
    for (int kk = 0; kk < 9; ++kk)
      w16[(size_t)(cblk * 9 + kk) * 8192 + (q * 256 + co) * 8 + j] =
        (hf)w_dcn[(size_t)co * KTOT + c * 9 + kk];
  } else {
    const int ks = bx - 2304;
    const int cblk = ks / 9, kk = ks - cblk * 9;
    for (int idx = tid; idx < 1024; idx += 256) {
      int lk = idx >> 8, row = (idx >> 3) & 31, j = idx & 7;
      int c = cblk * 32 + lk * 8 + j;
      float v = (row < 27) ? w_off[(size_t)row * KTOT + c * 9 + kk] : 0.f;
      wo16[(size_t)ks * 1024 + idx] = (hf)v;
    }
  }
}

// ---------------- dcn_fused: offconv phase + transform + dcn phase ----------------
// 512 blocks, 256 thr (4 waves). Block = (b, pos0 64-pos tile).
// Phase 1: 27(->32) x 2304 offset GEMM for own tile -> sy/sx/m -> pidx/pwts (all in LDS).
// Phase 2: v12 main loop (HWC gather + packed-f16 combine + MFMA, 4x4 acc).
__global__ __launch_bounds__(256, 2) void dcn_fused_kernel(
    const hf* __restrict__ xt, const hf* __restrict__ w16,
    const hf* __restrict__ wo16, const float* __restrict__ b_off,
    const float* __restrict__ b_dcn, float* __restrict__ out)
{
  __shared__ hf B_lds[2][8 * PQ];      // 16.6 KB (phase transition aliases stage here)
  __shared__ int2   pidx[576];
  __shared__ float4 pwts[576];

  const int tid  = threadIdx.x;
  const int b    = blockIdx.x & 7;
  const int pos0 = (blockIdx.x >> 3) * 64;

  const int lane = tid & 63, wid = tid >> 6;
  const int lm = lane & 15, lk = lane >> 4;
  const int gp = tid >> 2;                     // pos 0..63
  const int gh = tid & 3;                      // 8-ch chunk / q
  const int gpos = pos0 + gp;
  const int gho = gpos >> 6, gwo = gpos & 63;

  const hf* bt = xt + (size_t)b * HW * 256;
  const hfx8 zv = {};

  // ================= Phase 1: offset conv =================
  {
    f32x4 oacc[2];
    oacc[0] = (f32x4){0.f, 0.f, 0.f, 0.f};
    oacc[1] = (f32x4){0.f, 0.f, 0.f, 0.f};
    const hf* wga = wo16 + ((lk * 32 + lm) << 3);

    hfx8 gA, gB;
    bool vA, vB;

#define OG(S, T, CB)                                                     \
    {                                                                    \
      int ky = (T) / 3, kx = (T) - 3 * (ky);                             \
      int yy = gho + ky - 1, xx = gwo + kx - 1;                          \
      v##S = ((unsigned)yy < 64u) && ((unsigned)xx < 64u);               \
      int row = gpos + (ky - 1) * 64 + (kx - 1);                         \
      row = min(max(row, 0), HW - 1);                                    \
      g##S = *(const hfx8*)(bt + ((size_t)row << 8) + (CB) + gh * 8);    \
    }

    OG(A, 0, 0); OG(B, 1, 0);
    *(hfx8*)&B_lds[0][gh * PQ + gp * 8]       = vA ? gA : zv;
    *(hfx8*)&B_lds[0][(4 + gh) * PQ + gp * 8] = vB ? gB : zv;
    OG(A, 2, 0); OG(B, 3, 0);
    asm volatile("s_waitcnt lgkmcnt(0)" ::: "memory");
    __builtin_amdgcn_sched_barrier(0);
    __builtin_amdgcn_s_barrier();

#pragma unroll 2
    for (int i = 0; i < NK2 - 1; ++i) {
      const int ri = i & 1, wi = ri ^ 1;
      const hf* wg0 = wga + (size_t)(2 * i) * 1024;
      hfx8 af00 = *(const hfx8*)(wg0);
      hfx8 af01 = *(const hfx8*)(wg0 + 128);
      hfx8 af10 = *(const hfx8*)(wg0 + 1024);
      hfx8 af11 = *(const hfx8*)(wg0 + 1024 + 128);

      hfx8 bf0 = *(const hfx8*)&B_lds[ri][lk * PQ + (wid * 16 + lm) * 8];
      hfx8 bf1 = *(const hfx8*)&B_lds[ri][(4 + lk) * PQ + (wid * 16 + lm) * 8];

      *(hfx8*)&B_lds[wi][gh * PQ + gp * 8]       = vA ? gA : zv;
      *(hfx8*)&B_lds[wi][(4 + gh) * PQ + gp * 8] = vB ? gB : zv;

      {
        int ks0 = 2 * i + 4; if (ks0 > 70) ks0 = 70;
        int dA = ks0 / 9; int tA = ks0 - dA * 9; int cbA = dA * 32;
        int ks1 = ks0 + 1;
        int dB = ks1 / 9; int tB = ks1 - dB * 9; int cbB = dB * 32;
        OG(A, tA, cbA); OG(B, tB, cbB);
      }

      oacc[0] = __builtin_amdgcn_mfma_f32_16x16x32_f16(af00, bf0, oacc[0], 0, 0, 0);
      oacc[1] = __builtin_amdgcn_mfma_f32_16x16x32_f16(af01, bf0, oacc[1], 0, 0, 0);
      oacc[0] = __builtin_amdgcn_mfma_f32_16x16x32_f16(af10, bf1, oacc[0], 0, 0, 0);
      oacc[1] = __builtin_amdgcn_mfma_f32_16x16x32_f16(af11, bf1, oacc[1], 0, 0, 0);

      asm volatile("s_waitcnt lgkmcnt(0)" ::: "memory");
      __builtin_amdgcn_sched_barrier(0);
      __builtin_amdgcn_s_barrier();
    }

    {
      const hf* wg0 = wga + (size_t)70 * 1024;
      hfx8 af00 = *(const hfx8*)(wg0);
      hfx8 af01 = *(const hfx8*)(wg0 + 128);
      hfx8 af10 = *(const hfx8*)(wg0 + 1024);
      hfx8 af11 = *(const hfx8*)(wg0 + 1024 + 128);
      hfx8 bf0 = *(const hfx8*)&B_lds[1][lk * PQ + (wid * 16 + lm) * 8];
      hfx8 bf1 = *(const hfx8*)&B_lds[1][(4 + lk) * PQ + (wid * 16 + lm) * 8];
      oacc[0] = __builtin_amdgcn_mfma_f32_16x16x32_f16(af00, bf0, oacc[0], 0, 0, 0);
      oacc[1] = __builtin_amdgcn_mfma_f32_16x16x32_f16(af01, bf0, oacc[1], 0, 0, 0);
      oacc[0] = __builtin_amdgcn_mfma_f32_16x16x32_f16(af10, bf1, oacc[0], 0, 0, 0);
      oacc[1] = __builtin_amdgcn_mfma_f32_16x16x32_f16(af11, bf1, oacc[1], 0, 0, 0);
    }
#undef OG

    // ---- transform: acc -> stage (aliased in B_lds) -> pidx/pwts
    float* stage = (float*)&B_lds[0][0];       // [32][66] floats = 8.4 KB
    __syncthreads();
#pragma unroll
    for (int fr = 0; fr < 2; ++fr)
#pragma unroll
      for (int r = 0; r < 4; ++r)
        stage[(fr * 16 + lk * 4 + r) * 66 + wid * 16 + lm] = oacc[fr][r];
    __syncthreads();
    for (int t = tid; t < 576; t += 256) {
      int kk = t >> 6, p = t & 63;
      int pos = pos0 + p;
      int ho = pos >> 6, wo = pos & 63;
      float sy = stage[(2 * kk) * 66 + p]     + b_off[2 * kk]     + (float)(ho - 1 + kk / 3);
      float sx = stage[(2 * kk + 1) * 66 + p] + b_off[2 * kk + 1] + (float)(wo - 1 + kk % 3);
      float mv = stage[(18 + kk) * 66 + p]    + b_off[18 + kk];
      float m  = 1.f / (1.f + expf(-mv));
      float y0f = floorf(sy), x0f = floorf(sx);
      int y0 = (int)y0f, x0 = (int)x0f;
      float wy = sy - y0f, wx = sx - x0f;
      int ix0 = min(max(x0, 0), 63), ix1 = min(max(x0 + 1, 0), 63);
      int bx  = min(max(x0, 0), 62);
      float vx0 = (x0 >= 0  && x0 <= 63) ? 1.f : 0.f;
      float vx1 = (x0 >= -1 && x0 <= 62) ? 1.f : 0.f;
      float wx0 = (1.f - wx) * vx0, wx1 = wx * vx1;
      float a0 = (ix0 == bx     ? wx0 : 0.f) + (ix1 == bx     ? wx1 : 0.f);
      float a1 = (ix0 == bx + 1 ? wx0 : 0.f) + (ix1 == bx + 1 ? wx1 : 0.f);
      int rb0 = min(max(y0, 0), 63), rb1 = min(max(y0 + 1, 0), 63);
      float vy0 = (y0 >= 0  && y0 <= 63) ? 1.f : 0.f;
      float vy1 = (y0 >= -1 && y0 <= 62) ? 1.f : 0.f;
      float wy0m = (1.f - wy) * vy0 * m, wy1m = wy * vy1 * m;
      pidx[t] = make_int2(rb0 * 64 + bx, rb1 * 64 + bx);
      pwts[t] = make_float4(a0 * wy0m, a1 * wy0m, a0 * wy1m, a1 * wy1m);
    }
    __syncthreads();
  }

  // ================= Phase 2: main DCN GEMM (v12) =================
  const int chq = tid & 3;

  f32x4 acc[4][4];
#pragma unroll
  for (int a = 0; a < 4; ++a)
#pragma unroll
    for (int c = 0; c < 4; ++c)
      acc[a][c] = (f32x4){0.f, 0.f, 0.f, 0.f};

  const hf* wga = w16 + ((lk * 256 + wid * 64 + lm) << 3);
  const int wA = chq * PQ + gp * 8;
  const int wB = (4 + chq) * PQ + gp * 8;

  hf hwA0, hwA1, hwA2, hwA3, hwB0, hwB1, hwB2, hwB3;
  hfx8 cA00, cA01, cA10, cA11, cB00, cB01, cB10, cB11;

#define GATH(S, T, CB)                                                   \
  {                                                                      \
    int pb = (T) * 64 + gp;                                              \
    int2 pi = pidx[pb]; float4 pw = pwts[pb];                            \
    hw##S##0 = (hf)pw.x; hw##S##1 = (hf)pw.y;                            \
    hw##S##2 = (hf)pw.z; hw##S##3 = (hf)pw.w;                            \
    const hf* p0 = bt + ((size_t)pi.x << 8) + (CB) + (chq << 3);         \
    const hf* p1 = bt + ((size_t)pi.y << 8) + (CB) + (chq << 3);         \
    c##S##00 = *(const hfx8*)p0; c##S##01 = *(const hfx8*)(p0 + 256);    \
    c##S##10 = *(const hfx8*)p1; c##S##11 = *(const hfx8*)(p1 + 256);    \
  }

#define COMB(S, DST)                                                     \
  {                                                                      \
    hfx8 vv = c##S##00 * hw##S##0;                                       \
    vv += c##S##01 * hw##S##1;                                           \
    vv += c##S##10 * hw##S##2;                                           \
    vv += c##S##11 * hw##S##3;                                           \
    *(hfx8*)(DST) = vv;                                                  \
  }

  GATH(A, 0, 0); GATH(B, 1, 0);
  COMB(A, &B_lds[0][wA]);
  COMB(B, &B_lds[0][wB]);
  GATH(A, 2, 0); GATH(B, 3, 0);
  asm volatile("s_waitcnt lgkmcnt(0)" ::: "memory");
  __builtin_amdgcn_sched_barrier(0);
  __builtin_amdgcn_s_barrier();

#pragma unroll 2
  for (int i = 0; i < NK2 - 1; ++i) {
    const int ri = i & 1, wi = ri ^ 1;

    const hf* wg0 = wga + (size_t)(2 * i) * 8192;
    hfx8 af0[4], af1[4];
#pragma unroll
    for (int fr = 0; fr < 4; ++fr) af0[fr] = *(const hfx8*)(wg0 + fr * 128);

    hfx8 bf0[4], bf1[4];
#pragma unroll
    for (int pf = 0; pf < 4; ++pf)
      bf0[pf] = *(const hfx8*)&B_lds[ri][lk * PQ + (pf * 16 + lm) * 8];
#pragma unroll
    for (int fr = 0; fr < 4; ++fr) af1[fr] = *(const hfx8*)(wg0 + 8192 + fr * 128);
#pragma unroll
    for (int pf = 0; pf < 4; ++pf)
      bf1[pf] = *(const hfx8*)&B_lds[ri][(4 + lk) * PQ + (pf * 16 + lm) * 8];

    COMB(A, &B_lds[wi][wA]);
    COMB(B, &B_lds[wi][wB]);

    {
      int ks0 = 2 * i + 4; if (ks0 > 70) ks0 = 70;
      int dA = ks0 / 9; int tA = ks0 - dA * 9; int cbA = dA * 32;
      int ks1 = ks0 + 1;
      int dB = ks1 / 9; int tB = ks1 - dB * 9; int cbB = dB * 32;
      GATH(A, tA, cbA); GATH(B, tB, cbB);
    }

#pragma unroll
    for (int fr = 0; fr < 4; ++fr)
#pragma unroll
      for (int pf = 0; pf < 4; ++pf)
        acc[fr][pf] = __builtin_amdgcn_mfma_f32_16x16x32_f16(af0[fr], bf0[pf], acc[fr][pf], 0, 0, 0);
#pragma unroll
    for (int fr = 0; fr < 4; ++fr)
#pragma unroll
      for (int pf = 0; pf < 4; ++pf)
        acc[fr][pf] = __builtin_amdgcn_mfma_f32_16x16x32_f16(af1[fr], bf1[pf], acc[fr][pf], 0, 0, 0);

    asm volatile("s_waitcnt lgkmcnt(0)" ::: "memory");
    __builtin_amdgcn_sched_barrier(0);
    __builtin_amdgcn_s_barrier();
  }

  {
    const hf* wg0 = wga + (size_t)70 * 8192;
    hfx8 af0[4], af1[4];
#pragma unroll
    for (int fr = 0; fr < 4; ++fr) af0[fr] = *(const hfx8*)(wg0 + fr * 128);
#pragma unroll
    for (int fr = 0; fr < 4; ++fr) af1[fr] = *(const hfx8*)(wg0 + 8192 + fr * 128);
    hfx8 bf0[4], bf1[4];
#pragma unroll
    for (int pf = 0; pf < 4; ++pf) {
      bf0[pf] = *(const hfx8*)&B_lds[1][lk * PQ + (pf * 16 + lm) * 8];
      bf1[pf] = *(const hfx8*)&B_lds[1][(4 + lk) * PQ + (pf * 16 + lm) * 8];
    }
#pragma unroll
    for (int fr = 0; fr < 4; ++fr)
#pragma unroll
      for (int pf = 0; pf < 4; ++pf)
        acc[fr][pf] = __builtin_amdgcn_mfma_f32_16x16x32_f16(af0[fr], bf0[pf], acc[fr][pf], 0, 0, 0);
#pragma unroll
    for (int fr = 0; fr < 4; ++fr)
#pragma unroll
      for (int pf = 0; pf < 4; ++pf)
        acc[fr][pf] = __builtin_amdgcn_mfma_f32_16x16x32_f16(af1[fr], bf1[pf], acc[fr][pf], 0, 0, 0);
  }
#undef GATH
#undef COMB

  // ---- epilogue: bias + store (C/D: col=lane&15, row=(lane>>4)*4+reg)
#pragma unroll
  for (int fr = 0; fr < 4; ++fr) {
#pragma unroll
    for (int r = 0; r < 4; ++r) {
      int co = wid * 64 + fr * 16 + lk * 4 + r;
      float bias = b_dcn[co];
      float* orow = out + ((size_t)b * COUT + co) * HW + pos0;
#pragma unroll
      for (int pf = 0; pf < 4; ++pf)
        orow[pf * 16 + lm] = acc[fr][pf][r] + bias;
    }
  }
}

extern "C" void kernel_launch(void* const* d_in, const int* in_sizes, int n_in,
                              void* d_out, int out_size, void* d_ws, size_t ws_size,
                              hipStream_t stream) {
  const float* x     = (const float*)d_in[0];
  const float* w_off = (const float*)d_in[1];
  const float* b_off = (const float*)d_in[2];
  const float* w_dcn = (const float*)d_in[3];
  const float* b_dcn = (const float*)d_in[4];
  float* out = (float*)d_out;
  float* ws  = (float*)d_ws;
  hf* w16  = (hf*)(ws + 3 * WS_N);

  // Fused path requires xt+wo16 scratch (ws >= ~25.4 MB; harness provides >= this
  // since NEED3 passed in all prior rounds). Minimal-space fallback carves xt at
  // the front of ws (sy/sx/m arrays unused by the fused kernel).
  hf* xt;
  hf* wo16;
  if (ws_size >= NEED4) {
    xt   = (hf*)(ws + XT_OFF);
    wo16 = (hf*)(ws + WO16_OFF);
  } else {
    xt   = (hf*)ws;                          // 8 MB
    wo16 = (hf*)(ws + (BB * HW * CIN) / 2);  // +144 KB; w16 at 3*WS_N still free
  }

  prep_kernel<<<2376, 256, 0, stream>>>(x, w_dcn, w_off, xt, w16, wo16);
  dcn_fused_kernel<<<BB * (HW / 64), 256, 0, stream>>>(xt, w16, wo16, b_off, b_dcn, out);
}